// Round 1
// baseline (738.656 us; speedup 1.0000x reference)
//
#include <hip/hip_runtime.h>
#include <math.h>

// Problem constants
#define NB 4096          // batch B -> one block per b
#define CC 128           // channels (GEMM K)
#define TT 10
#define JJ 22
#define MM 220           // sites per b = T*J (GEMM M, padded to 224 = 14 tiles)
#define WSTRIDE 68       // uint32 words per Wb row (136 bf16 = 128 + 8 pad)
#define OUT0_N 19824640  // 4096*10*22*22
#define OUT1_N 9011200   // 4096*22*10*10

typedef __attribute__((ext_vector_type(8))) short bf16x8;
typedef __attribute__((ext_vector_type(4))) float f32x4;

// fp32 -> bf16 bits, round-to-nearest-even
__device__ __forceinline__ unsigned f2bf(float f) {
  union { float f; unsigned u; } v; v.f = f;
  return (v.u + 0x7FFFu + ((v.u >> 16) & 1u)) >> 16;
}

// Key math fact: softmax_j(s_i + d_j) == softmax_j(d_j)  (s_i cancels),
// so a_src_* is dead and out[g,i,j] = softmax(d)[j] + bias[i,j].
__global__ __launch_bounds__(448, 4) void dms_fused(
    const float* __restrict__ src,
    const float* __restrict__ Ws,
    const float* __restrict__ a_dst_s,
    const float* __restrict__ Wt,
    const float* __restrict__ a_dst_t,
    const float* __restrict__ sa_bias,
    const float* __restrict__ ta_bias,
    float* __restrict__ out)
{
  __shared__ unsigned lds_w[256 * WSTRIDE];  // Wb bf16 [256][136] = 69632 B
  __shared__ float a_l[256];                 // a_dst_s ++ a_dst_t
  __shared__ float ds_l[MM];                 // d_s per site
  __shared__ float dt_l[MM];                 // d_t per site

  const int tid  = threadIdx.x;
  const int w    = tid >> 6;     // wave 0..6
  const int lane = tid & 63;
  const int l15  = lane & 15;
  const int quad = lane >> 4;
  const int b    = blockIdx.x;

  const float* srcb = src + (size_t)b * (CC * MM);

  // ---- A fragments: direct global loads, cvt to bf16 ----
  // MFMA A layout (16x16x32): A[m = lane&15][k = quad*8 + j]
  // src[b,c,m] layout: c-major, m contiguous -> lanes 0..15 coalesce per load.
  bf16x8 Aa[2][4];
  #pragma unroll
  for (int mtp = 0; mtp < 2; ++mtp) {
    int m = (w * 2 + mtp) * 16 + l15;
    if (m > MM - 1) m = MM - 1;  // clamp: rows >=220 are dead, never written
    #pragma unroll
    for (int kf = 0; kf < 4; ++kf) {
      const float* p = srcb + (kf * 32 + quad * 8) * MM + m;
      bf16x8 f;
      #pragma unroll
      for (int j = 0; j < 8; ++j)
        f[j] = (short)f2bf(p[j * MM]);
      Aa[mtp][kf] = f;
    }
  }

  // ---- stage Wb = [W_s ; W_t] as bf16 into padded LDS rows ----
  for (int p4 = tid; p4 < 256 * 64; p4 += 448) {
    int n = p4 >> 6, kw = p4 & 63;
    const float* wp = (n < 128) ? (Ws + n * CC + kw * 2)
                                : (Wt + (n - 128) * CC + kw * 2);
    lds_w[n * WSTRIDE + kw] = f2bf(wp[0]) | (f2bf(wp[1]) << 16);
  }
  if (tid < 256)
    a_l[tid] = (tid < 128) ? a_dst_s[tid] : a_dst_t[tid - 128];
  __syncthreads();

  // ---- GEMM: x = A @ Wb^T, fused lrelu + a-weighted reduce over n ----
  // C/D layout: col = lane&15 (n), row = quad*4 + r (m)
  f32x4 part_s0 = {0,0,0,0}, part_s1 = {0,0,0,0};
  f32x4 part_t0 = {0,0,0,0}, part_t1 = {0,0,0,0};
  const unsigned short* wl = (const unsigned short*)lds_w;
  #pragma unroll
  for (int nt = 0; nt < 16; ++nt) {
    // B layout: B[k][n] = Wb[n][k]; lane holds n = nt*16 + l15, k-strip quad*8+j
    const bf16x8* bp = (const bf16x8*)(wl + (nt * 16 + l15) * (WSTRIDE * 2) + quad * 8);
    f32x4 acc0 = {0,0,0,0}, acc1 = {0,0,0,0};
    #pragma unroll
    for (int kf = 0; kf < 4; ++kf) {
      bf16x8 bb = bp[kf * 4];
      acc0 = __builtin_amdgcn_mfma_f32_16x16x32_bf16(Aa[0][kf], bb, acc0, 0, 0, 0);
      acc1 = __builtin_amdgcn_mfma_f32_16x16x32_bf16(Aa[1][kf], bb, acc1, 0, 0, 0);
    }
    float av = a_l[nt * 16 + l15];
    #pragma unroll
    for (int r = 0; r < 4; ++r) {
      float x0 = acc0[r]; x0 = (x0 >= 0.f) ? x0 : 0.2f * x0;
      float x1 = acc1[r]; x1 = (x1 >= 0.f) ? x1 : 0.2f * x1;
      if (nt < 8) { part_s0[r] += av * x0; part_s1[r] += av * x1; }
      else        { part_t0[r] += av * x0; part_t1[r] += av * x1; }
    }
  }

  // reduce across the 16 lanes sharing a row (low 4 lane bits)
  #pragma unroll
  for (int mk = 1; mk <= 8; mk <<= 1) {
    #pragma unroll
    for (int r = 0; r < 4; ++r) {
      part_s0[r] += __shfl_xor(part_s0[r], mk);
      part_s1[r] += __shfl_xor(part_s1[r], mk);
      part_t0[r] += __shfl_xor(part_t0[r], mk);
      part_t1[r] += __shfl_xor(part_t1[r], mk);
    }
  }
  if (l15 == 0) {
    #pragma unroll
    for (int r = 0; r < 4; ++r) {
      int m0 = (w * 2) * 16 + quad * 4 + r;
      if (m0 < MM) { ds_l[m0] = part_s0[r]; dt_l[m0] = part_t0[r]; }
      int m1 = (w * 2 + 1) * 16 + quad * 4 + r;
      if (m1 < MM) { ds_l[m1] = part_s1[r]; dt_l[m1] = part_t1[r]; }
    }
  }
  __syncthreads();

  // ---- spatial epilogue: softmax over j per (b,t); out0[b,t,i,j] ----
  for (int t = w; t < TT; t += 7) {
    float e = (lane < JJ) ? ds_l[t * JJ + lane] : -1e30f;
    float mx = e;
    #pragma unroll
    for (int mk = 1; mk < 64; mk <<= 1) mx = fmaxf(mx, __shfl_xor(mx, mk));
    float pp = (lane < JJ) ? __expf(e - mx) : 0.f;
    float ss = pp;
    #pragma unroll
    for (int mk = 1; mk < 64; mk <<= 1) ss += __shfl_xor(ss, mk);
    pp = pp / ss;
    float* o = out + (size_t)(b * TT + t) * (JJ * JJ);
    #pragma unroll
    for (int base = 0; base < 484; base += 64) {
      int oi = base + lane;
      int jdx = oi % JJ;              // < 22 even for oi >= 484
      float v = __shfl(pp, jdx);      // all 64 lanes execute the shfl
      if (oi < 484) o[oi] = v + sa_bias[oi];
    }
  }

  // ---- temporal epilogue: softmax over t per (b,j); out1[b,j,i,t] ----
  float* out1 = out + (size_t)OUT0_N;
  for (int jdx = w; jdx < JJ; jdx += 7) {
    float e = (lane < TT) ? dt_l[lane * JJ + jdx] : -1e30f;
    float mx = e;
    #pragma unroll
    for (int mk = 1; mk < 64; mk <<= 1) mx = fmaxf(mx, __shfl_xor(mx, mk));
    float qq = (lane < TT) ? __expf(e - mx) : 0.f;
    float ss = qq;
    #pragma unroll
    for (int mk = 1; mk < 64; mk <<= 1) ss += __shfl_xor(ss, mk);
    qq = qq / ss;
    float* o = out1 + (size_t)(b * JJ + jdx) * (TT * TT);
    #pragma unroll
    for (int base = 0; base < 128; base += 64) {
      int oi = base + lane;
      int tdx = oi % TT;
      float v = __shfl(qq, tdx);
      if (oi < 100) o[oi] = v + ta_bias[oi];
    }
  }

  // 4 trailing scalar zeros of the output tuple
  if (b == 0 && tid < 4) out[(size_t)OUT0_N + OUT1_N + tid] = 0.f;
}

extern "C" void kernel_launch(void* const* d_in, const int* in_sizes, int n_in,
                              void* d_out, int out_size, void* d_ws, size_t ws_size,
                              hipStream_t stream) {
  const float* src = (const float*)d_in[0];
  const float* Ws  = (const float*)d_in[1];
  // d_in[2] = a_src_s, d_in[5] = a_src_t: mathematically dead (softmax cancel)
  const float* ads = (const float*)d_in[3];
  const float* Wt  = (const float*)d_in[4];
  const float* adt = (const float*)d_in[6];
  const float* sab = (const float*)d_in[7];
  const float* tab = (const float*)d_in[8];
  dms_fused<<<NB, 448, 0, stream>>>(src, Ws, ads, Wt, adt, sab, tab, (float*)d_out);
}